// Round 1
// baseline (3603.649 us; speedup 1.0000x reference)
//
#include <hip/hip_runtime.h>
#include <hip/hip_bf16.h>
#include <cstdint>

#define T_TOKENS 2048
#define HIDDEN 2048
#define INTER 1408
#define NEXP 16
#define TOPK 4
#define SINTER 2816
#define CAP 768

__device__ __forceinline__ float4 ld4(const float* p) {
  return *reinterpret_cast<const float4*>(p);
}

// ---------------- router: logits -> softmax -> top4 ----------------
__global__ __launch_bounds__(64) void router_kernel(
    const float* __restrict__ x, const float* __restrict__ wg,
    int* __restrict__ topi, float* __restrict__ topw)
{
  const int t = blockIdx.x;
  const int lane = threadIdx.x;
  float acc[NEXP];
#pragma unroll
  for (int e = 0; e < NEXP; ++e) acc[e] = 0.f;
  const float* xr = x + (size_t)t * HIDDEN;
  for (int i = lane; i < HIDDEN; i += 64) {
    float xv = xr[i];
#pragma unroll
    for (int e = 0; e < NEXP; ++e) acc[e] += xv * wg[e * HIDDEN + i];
  }
#pragma unroll
  for (int e = 0; e < NEXP; ++e) {
#pragma unroll
    for (int off = 32; off > 0; off >>= 1)
      acc[e] += __shfl_xor(acc[e], off);
  }
  // softmax over 16 (all lanes hold identical values now)
  float m = acc[0];
#pragma unroll
  for (int e = 1; e < NEXP; ++e) m = fmaxf(m, acc[e]);
  float p[NEXP];
  float s = 0.f;
#pragma unroll
  for (int e = 0; e < NEXP; ++e) { p[e] = expf(acc[e] - m); s += p[e]; }
  const float inv = 1.f / s;
#pragma unroll
  for (int e = 0; e < NEXP; ++e) p[e] *= inv;
  if (lane == 0) {
#pragma unroll
    for (int k = 0; k < TOPK; ++k) {
      float best = -1.f; int bi = 0;
#pragma unroll
      for (int e = 0; e < NEXP; ++e)
        if (p[e] > best) { best = p[e]; bi = e; }   // strict >: lowest idx on tie
      topi[t * TOPK + k] = bi;
      topw[t * TOPK + k] = best;  // ROUTED_SCALE = 1.0
      p[bi] = -1.f;
    }
  }
}

// ------------- stable partition: slot -> (expert,pos), exact cumsum order -------------
__global__ __launch_bounds__(1024) void partition_kernel(
    const int* __restrict__ topi, float* __restrict__ topw,
    int* __restrict__ rowtok, int* __restrict__ count)
{
  __shared__ int se[T_TOKENS * TOPK];
  for (int i = threadIdx.x; i < T_TOKENS * TOPK; i += 1024) se[i] = topi[i];
  __syncthreads();

  const int wave = threadIdx.x >> 6;   // 16 waves = 16 experts
  const int lane = threadIdx.x & 63;
  const uint64_t below = (lane == 0) ? 0ull : ((~0ull) >> (64 - lane));
  int base = 0;
  for (int c = 0; c < T_TOKENS * TOPK; c += 64) {
    int ev = se[c + lane];
    uint64_t mask = __ballot(ev == wave);
    if (ev == wave) {
      int my = base + __popcll(mask & below);
      if (my < CAP) rowtok[wave * CAP + my] = c + lane;   // slot id
      else          topw[c + lane] = 0.f;                 // capacity drop
    }
    base += __popcll(mask);
  }
  if (lane == 0) count[wave] = base < CAP ? base : CAP;
}

// ------------- generic fp32 tile GEMM: C = A @ B1 (FUSED: silu(A@B1)*(A@B3)) -------------
// 128x128 tile, BK=16, 256 threads, 8x8 per thread.
// rows != null: r -> rowlist[r]; A row = rowlist[r] >> arow_shift; C row = rowlist[r].
template<int FUSED>
__global__ __launch_bounds__(256, 2)
void gemm128(const float* __restrict__ Ab, int lda,
             const float* __restrict__ B1b, const float* __restrict__ B3b,
             long bstride, int ldb,
             float* __restrict__ Cb, int ldc,
             const int* __restrict__ rows, int arow_shift,
             const int* __restrict__ cnt_ptr, int Mfix, int K)
{
  const int e = blockIdx.z;
  const int M = cnt_ptr ? cnt_ptr[e] : Mfix;
  const int mt = blockIdx.y;
  if (mt * 128 >= M) return;
  const int n0 = blockIdx.x * 128;
  const int tid = threadIdx.x;

  const int* rowlist = rows ? rows + e * CAP : nullptr;
  const float* B1 = B1b + (long)e * bstride;

  __shared__ float As[16][132];
  __shared__ float Bs1[16][132];
  __shared__ float Bs3[FUSED ? 16 : 1][132];

  // A staging: thread loads float4 at (row = ar + h*64, k = aq..aq+3), stores transposed
  const int ar = tid >> 2;          // 0..63
  const int aq = (tid & 3) * 4;     // 0,4,8,12
  long aoff[2];
#pragma unroll
  for (int h = 0; h < 2; ++h) {
    int r = mt * 128 + ar + h * 64;
    if (r > M - 1) r = M - 1;
    int src = rowlist ? (rowlist[r] >> arow_shift) : r;
    aoff[h] = (long)src * lda + aq;
  }
  // B staging: thread loads 8 floats of row bk at col bn
  const int bk = tid >> 4;          // 0..15
  const int bn = (tid & 15) * 8;    // 0..120
  const float* b1p = B1 + (long)bk * ldb + n0 + bn;
  const float* b3p = nullptr;
  if constexpr (FUSED) b3p = B3b + (long)e * bstride + (long)bk * ldb + n0 + bn;

  float ag[8][8];
  float au[8][8];
#pragma unroll
  for (int i = 0; i < 8; ++i)
#pragma unroll
    for (int j = 0; j < 8; ++j) { ag[i][j] = 0.f; if constexpr (FUSED) au[i][j] = 0.f; }

  const int ty = tid >> 4;   // 0..15
  const int tx = tid & 15;   // 0..15

  for (int k0 = 0; k0 < K; k0 += 16) {
#pragma unroll
    for (int h = 0; h < 2; ++h) {
      float4 av = ld4(Ab + aoff[h] + k0);
      As[aq + 0][ar + h * 64] = av.x;
      As[aq + 1][ar + h * 64] = av.y;
      As[aq + 2][ar + h * 64] = av.z;
      As[aq + 3][ar + h * 64] = av.w;
    }
    {
      const float* bp = b1p + (long)k0 * ldb;
      float4 v0 = ld4(bp);
      float4 v1 = ld4(bp + 4);
      *reinterpret_cast<float4*>(&Bs1[bk][bn]) = v0;
      *reinterpret_cast<float4*>(&Bs1[bk][bn + 4]) = v1;
    }
    if constexpr (FUSED) {
      const float* bp = b3p + (long)k0 * ldb;
      float4 v0 = ld4(bp);
      float4 v1 = ld4(bp + 4);
      *reinterpret_cast<float4*>(&Bs3[bk][bn]) = v0;
      *reinterpret_cast<float4*>(&Bs3[bk][bn + 4]) = v1;
    }
    __syncthreads();
#pragma unroll
    for (int kk = 0; kk < 16; ++kk) {
      float a[8], b[8], c[8];
      *reinterpret_cast<float4*>(&a[0]) = ld4(&As[kk][ty * 4]);
      *reinterpret_cast<float4*>(&a[4]) = ld4(&As[kk][ty * 4 + 64]);
      *reinterpret_cast<float4*>(&b[0]) = ld4(&Bs1[kk][tx * 4]);
      *reinterpret_cast<float4*>(&b[4]) = ld4(&Bs1[kk][tx * 4 + 64]);
      if constexpr (FUSED) {
        *reinterpret_cast<float4*>(&c[0]) = ld4(&Bs3[kk][tx * 4]);
        *reinterpret_cast<float4*>(&c[4]) = ld4(&Bs3[kk][tx * 4 + 64]);
      }
#pragma unroll
      for (int i = 0; i < 8; ++i)
#pragma unroll
        for (int j = 0; j < 8; ++j) {
          ag[i][j] = fmaf(a[i], b[j], ag[i][j]);
          if constexpr (FUSED) au[i][j] = fmaf(a[i], c[j], au[i][j]);
        }
    }
    __syncthreads();
  }

  // epilogue
#pragma unroll
  for (int i = 0; i < 8; ++i) {
    const int lr = (i < 4) ? (ty * 4 + i) : (64 + ty * 4 + (i - 4));
    const int r = mt * 128 + lr;
    if (r >= M) continue;
    const int crow = rowlist ? rowlist[r] : r;
    float* cp = Cb + (long)crow * ldc + n0;
    float outv[8];
    if constexpr (FUSED) {
#pragma unroll
      for (int j = 0; j < 8; ++j) {
        float g = ag[i][j];
        float sg = g / (1.f + expf(-g));   // silu
        outv[j] = sg * au[i][j];
      }
    } else {
#pragma unroll
      for (int j = 0; j < 8; ++j) outv[j] = ag[i][j];
    }
    *reinterpret_cast<float4*>(cp + tx * 4)      = *reinterpret_cast<float4*>(&outv[0]);
    *reinterpret_cast<float4*>(cp + tx * 4 + 64) = *reinterpret_cast<float4*>(&outv[4]);
  }
}

// ------------- combine: out[t] += sum_k w_k * o_slot[t*4+k] -------------
__global__ __launch_bounds__(256) void combine_kernel(
    const float* __restrict__ o_slot, const float* __restrict__ topw,
    float* __restrict__ out)
{
  const int t = blockIdx.x;
  float w[TOPK];
#pragma unroll
  for (int k = 0; k < TOPK; ++k) w[k] = topw[t * TOPK + k];
  float* orow = out + (size_t)t * HIDDEN;
  for (int c = threadIdx.x * 4; c < HIDDEN; c += 256 * 4) {
    float4 acc = *reinterpret_cast<float4*>(orow + c);
#pragma unroll
    for (int k = 0; k < TOPK; ++k) {
      if (w[k] != 0.f) {
        float4 v = ld4(o_slot + ((size_t)(t * TOPK + k)) * HIDDEN + c);
        acc.x += w[k] * v.x; acc.y += w[k] * v.y;
        acc.z += w[k] * v.z; acc.w += w[k] * v.w;
      }
    }
    *reinterpret_cast<float4*>(orow + c) = acc;
  }
}

extern "C" void kernel_launch(void* const* d_in, const int* in_sizes, int n_in,
                              void* d_out, int out_size, void* d_ws, size_t ws_size,
                              hipStream_t stream)
{
  const float* x   = (const float*)d_in[0];
  const float* wg  = (const float*)d_in[1];
  const float* w1  = (const float*)d_in[2];
  const float* w3  = (const float*)d_in[3];
  const float* w2  = (const float*)d_in[4];
  const float* ws1 = (const float*)d_in[5];
  const float* ws3 = (const float*)d_in[6];
  const float* ws2 = (const float*)d_in[7];
  float* out = (float*)d_out;

  char* w = (char*)d_ws;
  int*   topi   = (int*)w;   w += (size_t)T_TOKENS * TOPK * 4;
  float* topw   = (float*)w; w += (size_t)T_TOKENS * TOPK * 4;
  int*   rowtok = (int*)w;   w += (size_t)NEXP * CAP * 4;
  int*   count  = (int*)w;   w += 256;
  uintptr_t a = (uintptr_t)w; a = (a + 255) & ~(uintptr_t)255; w = (char*)a;
  // hbuf shared between: shared-FFN hs [2048 x 2816] and routed h_slot [8192 x 1408]
  float* hbuf = (float*)w;   w += (size_t)T_TOKENS * TOPK * INTER * 4;  // 46.1 MB (>= hs 23.1 MB)
  float* o_slot = (float*)w; w += (size_t)T_TOKENS * TOPK * HIDDEN * 4; // 67.1 MB

  router_kernel<<<T_TOKENS, 64, 0, stream>>>(x, wg, topi, topw);
  partition_kernel<<<1, 1024, 0, stream>>>(topi, topw, rowtok, count);

  // shared experts first (hs lives in hbuf, then freed for h_slot)
  gemm128<1><<<dim3(SINTER / 128, T_TOKENS / 128, 1), 256, 0, stream>>>(
      x, HIDDEN, ws1, ws3, 0, SINTER, hbuf, SINTER,
      nullptr, 0, nullptr, T_TOKENS, HIDDEN);
  gemm128<0><<<dim3(HIDDEN / 128, T_TOKENS / 128, 1), 256, 0, stream>>>(
      hbuf, SINTER, ws2, nullptr, 0, HIDDEN, out, HIDDEN,
      nullptr, 0, nullptr, T_TOKENS, SINTER);

  // routed experts: h_slot = silu(x@w1)*(x@w3) gathered per expert
  gemm128<1><<<dim3(INTER / 128, (CAP + 127) / 128, NEXP), 256, 0, stream>>>(
      x, HIDDEN, w1, w3, (long)HIDDEN * INTER, INTER, hbuf, INTER,
      rowtok, 2, count, 0, HIDDEN);
  // o_slot = h_slot @ w2
  gemm128<0><<<dim3(HIDDEN / 128, (CAP + 127) / 128, NEXP), 256, 0, stream>>>(
      hbuf, INTER, w2, nullptr, (long)INTER * HIDDEN, HIDDEN, o_slot, HIDDEN,
      rowtok, 0, count, 0, INTER);

  combine_kernel<<<T_TOKENS, 256, 0, stream>>>(o_slot, topw, out);
}

// Round 2
// 1304.579 us; speedup vs baseline: 2.7623x; 2.7623x over previous
//
#include <hip/hip_runtime.h>
#include <hip/hip_bf16.h>
#include <cstdint>

#define T_TOKENS 2048
#define HIDDEN 2048
#define INTER 1408
#define NEXP 16
#define TOPK 4
#define SINTER 2816
#define CAP 768

typedef __attribute__((ext_vector_type(8))) short short8;
typedef __attribute__((ext_vector_type(8))) unsigned short ushort8;
typedef __attribute__((ext_vector_type(4))) float f32x4;

__device__ __forceinline__ float4 ld4f(const float* p) {
  return *reinterpret_cast<const float4*>(p);
}

// bf16 split: v ~= hi + lo, each bf16 (RNE). |v - hi - lo| <~ 2^-17 |v|
__device__ __forceinline__ unsigned short f2bf(float v) {
  unsigned int u = __float_as_uint(v);
  unsigned int r = (u + 0x7FFFu + ((u >> 16) & 1u)) >> 16;
  return (unsigned short)r;
}
__device__ __forceinline__ float bf2f(unsigned short b) {
  return __uint_as_float(((unsigned int)b) << 16);
}
__device__ __forceinline__ void bsplit(float v, unsigned short& h, unsigned short& l) {
  h = f2bf(v);
  l = f2bf(v - bf2f(h));
}

// ---------------- router: logits -> softmax -> top4 ----------------
__global__ __launch_bounds__(64) void router_kernel(
    const float* __restrict__ x, const float* __restrict__ wg,
    int* __restrict__ topi, float* __restrict__ topw)
{
  const int t = blockIdx.x;
  const int lane = threadIdx.x;
  float acc[NEXP];
#pragma unroll
  for (int e = 0; e < NEXP; ++e) acc[e] = 0.f;
  const float* xr = x + (size_t)t * HIDDEN;
  for (int i = lane; i < HIDDEN; i += 64) {
    float xv = xr[i];
#pragma unroll
    for (int e = 0; e < NEXP; ++e) acc[e] += xv * wg[e * HIDDEN + i];
  }
#pragma unroll
  for (int e = 0; e < NEXP; ++e) {
#pragma unroll
    for (int off = 32; off > 0; off >>= 1)
      acc[e] += __shfl_xor(acc[e], off);
  }
  float m = acc[0];
#pragma unroll
  for (int e = 1; e < NEXP; ++e) m = fmaxf(m, acc[e]);
  float p[NEXP];
  float s = 0.f;
#pragma unroll
  for (int e = 0; e < NEXP; ++e) { p[e] = expf(acc[e] - m); s += p[e]; }
  const float inv = 1.f / s;
#pragma unroll
  for (int e = 0; e < NEXP; ++e) p[e] *= inv;
  if (lane == 0) {
#pragma unroll
    for (int k = 0; k < TOPK; ++k) {
      float best = -1.f; int bi = 0;
#pragma unroll
      for (int e = 0; e < NEXP; ++e)
        if (p[e] > best) { best = p[e]; bi = e; }   // strict >: lowest idx on tie
      topi[t * TOPK + k] = bi;
      topw[t * TOPK + k] = best;  // ROUTED_SCALE = 1.0
      p[bi] = -1.f;
    }
  }
}

// ------------- stable partition: slot -> (expert,pos), exact cumsum order -------------
__global__ __launch_bounds__(1024) void partition_kernel(
    const int* __restrict__ topi, float* __restrict__ topw,
    int* __restrict__ rowtok, int* __restrict__ count)
{
  __shared__ int se[T_TOKENS * TOPK];
  for (int i = threadIdx.x; i < T_TOKENS * TOPK; i += 1024) se[i] = topi[i];
  __syncthreads();

  const int wave = threadIdx.x >> 6;   // 16 waves = 16 experts
  const int lane = threadIdx.x & 63;
  const uint64_t below = (lane == 0) ? 0ull : ((~0ull) >> (64 - lane));
  int base = 0;
  for (int c = 0; c < T_TOKENS * TOPK; c += 64) {
    int ev = se[c + lane];
    uint64_t mask = __ballot(ev == wave);
    if (ev == wave) {
      int my = base + __popcll(mask & below);
      if (my < CAP) rowtok[wave * CAP + my] = c + lane;   // slot id
      else          topw[c + lane] = 0.f;                 // capacity drop
    }
    base += __popcll(mask);
  }
  if (lane == 0) count[wave] = base < CAP ? base : CAP;
}

// ------------- split-bf16 MFMA GEMM: C = A @ B (EPI=1: C = silu(G)*acc) -------------
// 128x128 tile, BK=32, 256 threads = 4 waves (2x2), wave tile 64x64,
// mfma_f32_16x16x32_bf16, 3 MFMAs per fragment pair (hh + hl + lh).
#define LDS_S 40   // LDS row stride in ushorts (80 B; /4 = 20 -> conflict-light)

template<int EPI>
__global__ __launch_bounds__(256, 2)
void gemm_mfma(const float* __restrict__ Ab, int lda,
               const float* __restrict__ Bb, long bstride, int ldb,
               float* __restrict__ Cb, int ldc,
               const float* __restrict__ Gb,
               const int* __restrict__ rows, int arow_shift,
               const int* __restrict__ cnt, int Mfix, int K)
{
  const int e = blockIdx.z;
  const int M = cnt ? cnt[e] : Mfix;
  const int mt = blockIdx.y;
  if (mt * 128 >= M) return;
  const int n0 = blockIdx.x * 128;
  const int tid = threadIdx.x;
  const int lane = tid & 63;
  const int wave = tid >> 6;
  const int wr = (wave >> 1) * 64;
  const int wc = (wave & 1) * 64;

  const int* rowlist = rows ? rows + e * CAP : nullptr;
  const float* B = Bb + (long)e * bstride;

  __shared__ unsigned short Ahi[128][LDS_S];
  __shared__ unsigned short Alo[128][LDS_S];
  __shared__ unsigned short Bhi[128][LDS_S];
  __shared__ unsigned short Blo[128][LDS_S];

  // staging maps: A: thread -> (row=tid>>1, k=(tid&1)*16 .. +15)
  const int ar = tid >> 1;
  const int ak = (tid & 1) * 16;
  int arow;
  {
    int r = mt * 128 + ar;
    if (r > M - 1) r = M - 1;
    arow = rowlist ? (rowlist[r] >> arow_shift) : r;
  }
  const float* aptr = Ab + (long)arow * lda + ak;

  // B: thread -> (col=tid&127, k=(tid>>7)*16 .. +15); lanes contiguous in n
  const int bn = tid & 127;
  const int bk = (tid >> 7) * 16;
  const float* bptr = B + (long)bk * ldb + n0 + bn;

  float4 av[4];
  float bv[16];
#pragma unroll
  for (int i = 0; i < 4; ++i) av[i] = ld4f(aptr + i * 4);
#pragma unroll
  for (int i = 0; i < 16; ++i) bv[i] = bptr[(long)i * ldb];

  f32x4 acc[4][4];
#pragma unroll
  for (int i = 0; i < 4; ++i)
#pragma unroll
    for (int j = 0; j < 4; ++j) acc[i][j] = (f32x4)0.f;

  const int fr = lane & 15;   // frag row (A) / col (B)
  const int fc = lane >> 4;   // k-chunk 0..3

  for (int kt = 0; kt < K; kt += 32) {
    __syncthreads();   // previous tile's fragment reads complete
    // ---- convert + write staged regs to LDS ----
    {
      unsigned short h[16], l[16];
      float vals[16] = {av[0].x, av[0].y, av[0].z, av[0].w,
                        av[1].x, av[1].y, av[1].z, av[1].w,
                        av[2].x, av[2].y, av[2].z, av[2].w,
                        av[3].x, av[3].y, av[3].z, av[3].w};
#pragma unroll
      for (int i = 0; i < 16; ++i) bsplit(vals[i], h[i], l[i]);
      *(ushort8*)&Ahi[ar][ak]     = *(ushort8*)&h[0];
      *(ushort8*)&Ahi[ar][ak + 8] = *(ushort8*)&h[8];
      *(ushort8*)&Alo[ar][ak]     = *(ushort8*)&l[0];
      *(ushort8*)&Alo[ar][ak + 8] = *(ushort8*)&l[8];
#pragma unroll
      for (int i = 0; i < 16; ++i) bsplit(bv[i], h[i], l[i]);
      *(ushort8*)&Bhi[bn][bk]     = *(ushort8*)&h[0];
      *(ushort8*)&Bhi[bn][bk + 8] = *(ushort8*)&h[8];
      *(ushort8*)&Blo[bn][bk]     = *(ushort8*)&l[0];
      *(ushort8*)&Blo[bn][bk + 8] = *(ushort8*)&l[8];
    }
    // ---- issue next tile's global loads (hide under MFMA phase) ----
    if (kt + 32 < K) {
#pragma unroll
      for (int i = 0; i < 4; ++i) av[i] = ld4f(aptr + kt + 32 + i * 4);
#pragma unroll
      for (int i = 0; i < 16; ++i) bv[i] = bptr[(long)(kt + 32 + i) * ldb];
    }
    __syncthreads();
    // ---- fragment reads + 48 MFMAs ----
    short8 fah[4], fal[4], fbh[4], fbl[4];
#pragma unroll
    for (int mi = 0; mi < 4; ++mi) {
      fah[mi] = *(const short8*)&Ahi[wr + mi * 16 + fr][fc * 8];
      fal[mi] = *(const short8*)&Alo[wr + mi * 16 + fr][fc * 8];
    }
#pragma unroll
    for (int ni = 0; ni < 4; ++ni) {
      fbh[ni] = *(const short8*)&Bhi[wc + ni * 16 + fr][fc * 8];
      fbl[ni] = *(const short8*)&Blo[wc + ni * 16 + fr][fc * 8];
    }
#pragma unroll
    for (int mi = 0; mi < 4; ++mi)
#pragma unroll
      for (int ni = 0; ni < 4; ++ni) {
        acc[mi][ni] = __builtin_amdgcn_mfma_f32_16x16x32_bf16(fah[mi], fbh[ni], acc[mi][ni], 0, 0, 0);
        acc[mi][ni] = __builtin_amdgcn_mfma_f32_16x16x32_bf16(fah[mi], fbl[ni], acc[mi][ni], 0, 0, 0);
        acc[mi][ni] = __builtin_amdgcn_mfma_f32_16x16x32_bf16(fal[mi], fbh[ni], acc[mi][ni], 0, 0, 0);
      }
  }

  // ---- epilogue: C/D frag layout col=lane&15, row=(lane>>4)*4+r ----
#pragma unroll
  for (int mi = 0; mi < 4; ++mi)
#pragma unroll
    for (int rr = 0; rr < 4; ++rr) {
      const int r = mt * 128 + wr + mi * 16 + fc * 4 + rr;
      if (r >= M) continue;
      const int crow = rowlist ? rowlist[r] : r;
#pragma unroll
      for (int ni = 0; ni < 4; ++ni) {
        const int col = n0 + wc + ni * 16 + fr;
        const long off = (long)crow * ldc + col;
        float v = acc[mi][ni][rr];
        if constexpr (EPI == 1) {
          float g = Gb[off];
          v = v * (g / (1.f + __expf(-g)));   // silu(g) * u
        }
        Cb[off] = v;
      }
    }
}

// ------------- combine: out[t] += sum_k w_k * o_slot[t*4+k] -------------
__global__ __launch_bounds__(256) void combine_kernel(
    const float* __restrict__ o_slot, const float* __restrict__ topw,
    float* __restrict__ out)
{
  const int t = blockIdx.x;
  float w[TOPK];
#pragma unroll
  for (int k = 0; k < TOPK; ++k) w[k] = topw[t * TOPK + k];
  float* orow = out + (size_t)t * HIDDEN;
  for (int c = threadIdx.x * 4; c < HIDDEN; c += 256 * 4) {
    float4 acc = *reinterpret_cast<float4*>(orow + c);
#pragma unroll
    for (int k = 0; k < TOPK; ++k) {
      if (w[k] != 0.f) {
        float4 v = ld4f(o_slot + ((size_t)(t * TOPK + k)) * HIDDEN + c);
        acc.x += w[k] * v.x; acc.y += w[k] * v.y;
        acc.z += w[k] * v.z; acc.w += w[k] * v.w;
      }
    }
    *reinterpret_cast<float4*>(orow + c) = acc;
  }
}

extern "C" void kernel_launch(void* const* d_in, const int* in_sizes, int n_in,
                              void* d_out, int out_size, void* d_ws, size_t ws_size,
                              hipStream_t stream)
{
  const float* x   = (const float*)d_in[0];
  const float* wg  = (const float*)d_in[1];
  const float* w1  = (const float*)d_in[2];
  const float* w3  = (const float*)d_in[3];
  const float* w2  = (const float*)d_in[4];
  const float* ws1 = (const float*)d_in[5];
  const float* ws3 = (const float*)d_in[6];
  const float* ws2 = (const float*)d_in[7];
  float* out = (float*)d_out;

  char* w = (char*)d_ws;
  int*   topi   = (int*)w;   w += (size_t)T_TOKENS * TOPK * 4;
  float* topw   = (float*)w; w += (size_t)T_TOKENS * TOPK * 4;
  int*   rowtok = (int*)w;   w += (size_t)NEXP * CAP * 4;
  int*   count  = (int*)w;   w += 256;
  uintptr_t a = (uintptr_t)w; a = (a + 255) & ~(uintptr_t)255; w = (char*)a;
  // gbuf region (67.1 MB): holds g_s [2048x2816], then g_r [8192x1408], then o_slot [8192x2048]
  float* gbuf   = (float*)w; w += (size_t)T_TOKENS * TOPK * HIDDEN * 4;
  // h_r [8192x1408] (46.2 MB)
  float* hbuf_r = (float*)w; w += (size_t)T_TOKENS * TOPK * INTER * 4;
  // h_s [2048x2816] (23.1 MB)
  float* hbuf_s = (float*)w; w += (size_t)T_TOKENS * SINTER * 4;

  router_kernel<<<T_TOKENS, 64, 0, stream>>>(x, wg, topi, topw);
  partition_kernel<<<1, 1024, 0, stream>>>(topi, topw, rowtok, count);

  // S1: g_s = x @ ws1
  gemm_mfma<0><<<dim3(SINTER / 128, T_TOKENS / 128, 1), 256, 0, stream>>>(
      x, HIDDEN, ws1, 0, SINTER, gbuf, SINTER, nullptr,
      nullptr, 0, nullptr, T_TOKENS, HIDDEN);
  // S2: h_s = silu(g_s) * (x @ ws3)
  gemm_mfma<1><<<dim3(SINTER / 128, T_TOKENS / 128, 1), 256, 0, stream>>>(
      x, HIDDEN, ws3, 0, SINTER, hbuf_s, SINTER, gbuf,
      nullptr, 0, nullptr, T_TOKENS, HIDDEN);
  // K1: g_r = gather(x) @ w1[e]   (rows: slot -> token = rowtok>>2)
  gemm_mfma<0><<<dim3(INTER / 128, (CAP + 127) / 128, NEXP), 256, 0, stream>>>(
      x, HIDDEN, w1, (long)HIDDEN * INTER, INTER, gbuf, INTER, nullptr,
      rowtok, 2, count, 0, HIDDEN);
  // K2: h_r = silu(g_r) * (gather(x) @ w3[e])
  gemm_mfma<1><<<dim3(INTER / 128, (CAP + 127) / 128, NEXP), 256, 0, stream>>>(
      x, HIDDEN, w3, (long)HIDDEN * INTER, INTER, hbuf_r, INTER, gbuf,
      rowtok, 2, count, 0, HIDDEN);
  // S3: out = h_s @ ws2
  gemm_mfma<0><<<dim3(HIDDEN / 128, T_TOKENS / 128, 1), 256, 0, stream>>>(
      hbuf_s, SINTER, ws2, 0, HIDDEN, out, HIDDEN, nullptr,
      nullptr, 0, nullptr, T_TOKENS, SINTER);
  // K3: o_slot = h_r @ w2[e]  (overwrites gbuf; g_r is dead after K2)
  gemm_mfma<0><<<dim3(HIDDEN / 128, (CAP + 127) / 128, NEXP), 256, 0, stream>>>(
      hbuf_r, INTER, w2, (long)INTER * HIDDEN, HIDDEN, gbuf, HIDDEN, nullptr,
      rowtok, 0, count, 0, INTER);

  combine_kernel<<<T_TOKENS, 256, 0, stream>>>(gbuf, topw, out);
}

// Round 3
// 1298.593 us; speedup vs baseline: 2.7750x; 1.0046x over previous
//
#include <hip/hip_runtime.h>
#include <hip/hip_bf16.h>
#include <cstdint>

#define T_TOKENS 2048
#define HIDDEN 2048
#define INTER 1408
#define NEXP 16
#define TOPK 4
#define SINTER 2816
#define CAP 768
#define BK 32

typedef __attribute__((ext_vector_type(8))) short short8;
typedef __attribute__((ext_vector_type(8))) unsigned short ushort8;
typedef __attribute__((ext_vector_type(4))) unsigned short ushort4v;
typedef __attribute__((ext_vector_type(4))) float f32x4;

__device__ __forceinline__ float4 ld4f(const float* p) {
  return *reinterpret_cast<const float4*>(p);
}

// bf16 split: v ~= hi + lo, each bf16 (RNE). |v - hi - lo| <~ 2^-17 |v|
__device__ __forceinline__ unsigned short f2bf(float v) {
  unsigned int u = __float_as_uint(v);
  unsigned int r = (u + 0x7FFFu + ((u >> 16) & 1u)) >> 16;
  return (unsigned short)r;
}
__device__ __forceinline__ float bf2f(unsigned short b) {
  return __uint_as_float(((unsigned int)b) << 16);
}
__device__ __forceinline__ void bsplit(float v, unsigned short& h, unsigned short& l) {
  h = f2bf(v);
  l = f2bf(v - bf2f(h));
}

__device__ __forceinline__ void gld16(const void* g, void* l) {
  __builtin_amdgcn_global_load_lds(
      (const __attribute__((address_space(1))) void*)g,
      (__attribute__((address_space(3))) void*)l, 16, 0, 0);
}

// ---------------- router: logits -> softmax -> top4 ----------------
__global__ __launch_bounds__(64) void router_kernel(
    const float* __restrict__ x, const float* __restrict__ wg,
    int* __restrict__ topi, float* __restrict__ topw)
{
  const int t = blockIdx.x;
  const int lane = threadIdx.x;
  float acc[NEXP];
#pragma unroll
  for (int e = 0; e < NEXP; ++e) acc[e] = 0.f;
  const float* xr = x + (size_t)t * HIDDEN;
  for (int i = lane; i < HIDDEN; i += 64) {
    float xv = xr[i];
#pragma unroll
    for (int e = 0; e < NEXP; ++e) acc[e] += xv * wg[e * HIDDEN + i];
  }
#pragma unroll
  for (int e = 0; e < NEXP; ++e) {
#pragma unroll
    for (int off = 32; off > 0; off >>= 1)
      acc[e] += __shfl_xor(acc[e], off);
  }
  float m = acc[0];
#pragma unroll
  for (int e = 1; e < NEXP; ++e) m = fmaxf(m, acc[e]);
  float p[NEXP];
  float s = 0.f;
#pragma unroll
  for (int e = 0; e < NEXP; ++e) { p[e] = expf(acc[e] - m); s += p[e]; }
  const float inv = 1.f / s;
#pragma unroll
  for (int e = 0; e < NEXP; ++e) p[e] *= inv;
  if (lane == 0) {
#pragma unroll
    for (int k = 0; k < TOPK; ++k) {
      float best = -1.f; int bi = 0;
#pragma unroll
      for (int e = 0; e < NEXP; ++e)
        if (p[e] > best) { best = p[e]; bi = e; }   // strict >: lowest idx on tie
      topi[t * TOPK + k] = bi;
      topw[t * TOPK + k] = best;  // ROUTED_SCALE = 1.0
      p[bi] = -1.f;
    }
  }
}

// ------------- stable partition: slot -> (expert,pos), exact cumsum order -------------
__global__ __launch_bounds__(1024) void partition_kernel(
    const int* __restrict__ topi, float* __restrict__ topw,
    int* __restrict__ rowtok, int* __restrict__ count)
{
  __shared__ int se[T_TOKENS * TOPK];
  for (int i = threadIdx.x; i < T_TOKENS * TOPK; i += 1024) se[i] = topi[i];
  __syncthreads();

  const int wave = threadIdx.x >> 6;   // 16 waves = 16 experts
  const int lane = threadIdx.x & 63;
  const uint64_t below = (lane == 0) ? 0ull : ((~0ull) >> (64 - lane));
  int base = 0;
  for (int c = 0; c < T_TOKENS * TOPK; c += 64) {
    int ev = se[c + lane];
    uint64_t mask = __ballot(ev == wave);
    if (ev == wave) {
      int my = base + __popcll(mask & below);
      if (my < CAP) rowtok[wave * CAP + my] = c + lane;   // slot id
      else          topw[c + lane] = 0.f;                 // capacity drop
    }
    base += __popcll(mask);
  }
  if (lane == 0) count[wave] = base < CAP ? base : CAP;
}

// ------------- elementwise split: x -> hi/lo planes -------------
__global__ __launch_bounds__(256) void split_x_kernel(
    const float* __restrict__ x, unsigned short* __restrict__ hi,
    unsigned short* __restrict__ lo)
{
  const long i = ((long)blockIdx.x * 256 + threadIdx.x) * 8;
  float4 a = ld4f(x + i), b = ld4f(x + i + 4);
  float v[8] = {a.x, a.y, a.z, a.w, b.x, b.y, b.z, b.w};
  unsigned short h[8], l[8];
#pragma unroll
  for (int j = 0; j < 8; ++j) bsplit(v[j], h[j], l[j]);
  *(ushort8*)(hi + i) = *(ushort8*)&h[0];
  *(ushort8*)(lo + i) = *(ushort8*)&l[0];
}

// ------------- transpose + split: W[K][N] -> T{hi,lo}[N][K] (per expert z) -------------
__global__ __launch_bounds__(256) void tsplit_w_kernel(
    const float* __restrict__ W, unsigned short* __restrict__ Thi,
    unsigned short* __restrict__ Tlo, int K, int N)
{
  const long z = blockIdx.z;
  W   += z * (long)K * N;
  Thi += z * (long)K * N;
  Tlo += z * (long)K * N;
  const int k0 = blockIdx.x * 64, n0 = blockIdx.y * 64;
  __shared__ float tile[64][65];
  const int tr = threadIdx.x >> 4;          // 0..15
  const int tc4 = (threadIdx.x & 15) * 4;   // 0..60
#pragma unroll
  for (int p = 0; p < 4; ++p) {
    int r = p * 16 + tr;
    float4 v = ld4f(W + (long)(k0 + r) * N + n0 + tc4);
    tile[r][tc4] = v.x; tile[r][tc4 + 1] = v.y;
    tile[r][tc4 + 2] = v.z; tile[r][tc4 + 3] = v.w;
  }
  __syncthreads();
#pragma unroll
  for (int p = 0; p < 4; ++p) {
    int n = p * 16 + tr;
    unsigned short h4[4], l4[4];
#pragma unroll
    for (int j = 0; j < 4; ++j) bsplit(tile[tc4 + j][n], h4[j], l4[j]);
    long off = (long)(n0 + n) * K + k0 + tc4;
    *(ushort4v*)(Thi + off) = *(ushort4v*)&h4[0];
    *(ushort4v*)(Tlo + off) = *(ushort4v*)&l4[0];
  }
}

// ------------- dual-plane bf16 MFMA GEMM (3 MFMA: hh+hl+lh), gload_lds staged -------------
// 128x128 tile, BK=32, 4 waves (2x2), wave tile 64x64, double-buffered LDS.
// A row: arows ? arows[r]>>ashift : e*aexp + r. C row: crows ? crows[r] : e*cexp + r.
template<int EPI>   // 0: C fp32; 1: read G fp32, write silu(G)*acc split into Chi/Clo
__global__ __launch_bounds__(256, 2)
void gemm_bf3(const unsigned short* __restrict__ Ahi_g, const unsigned short* __restrict__ Alo_g,
              int lda,
              const unsigned short* __restrict__ Bhi_g, const unsigned short* __restrict__ Blo_g,
              long bstride,
              float* __restrict__ C, unsigned short* __restrict__ Chi, unsigned short* __restrict__ Clo,
              int ldc, const float* __restrict__ G,
              const int* __restrict__ arows_g, int ashift, long aexp,
              const int* __restrict__ crows_g, long cexp,
              const int* __restrict__ cnt, int Mfix, int K)
{
  const int e = blockIdx.z;
  const int M = cnt ? cnt[e] : Mfix;
  const int mt = blockIdx.y;
  if (mt * 128 >= M) return;
  const int n0 = blockIdx.x * 128;
  const int tid = threadIdx.x;
  const int lane = tid & 63;
  const int wave = tid >> 6;
  const int wr = (wave >> 1) * 64;
  const int wc = (wave & 1) * 64;

  const int* arows = arows_g ? arows_g + e * CAP : nullptr;
  const int* crows = crows_g ? crows_g + e * CAP : nullptr;
  const unsigned short* Bhi = Bhi_g + (long)e * bstride;
  const unsigned short* Blo = Blo_g + (long)e * bstride;

  // [buf][plane][128 rows * 32 k] ushorts; rows are 64 B, linear (gload_lds friendly)
  __shared__ __align__(16) unsigned short sA[2][2][128 * BK];
  __shared__ __align__(16) unsigned short sB[2][2][128 * BK];

  // staging: wave w covers 16-row groups i = 2w, 2w+1 of each plane-array.
  // lane l -> row (l>>2) within group, 16B chunk (l&3). LDS dest = base + l*16 (linear).
  const int lr = lane >> 2;
  const int ch = lane & 3;
  long offA[2], offB[2];
#pragma unroll
  for (int j = 0; j < 2; ++j) {
    const int i = wave * 2 + j;
    const int rloc = i * 16 + lr;             // 0..127
    int r = mt * 128 + rloc;
    if (r > M - 1) r = M - 1;
    const long arow = arows ? (long)(arows[r] >> ashift) : (aexp * e + r);
    offA[j] = arow * lda + ch * 8;            // element offset
    offB[j] = (long)(n0 + rloc) * K + ch * 8;
  }

  f32x4 acc[4][4];
#pragma unroll
  for (int i = 0; i < 4; ++i)
#pragma unroll
    for (int j = 0; j < 4; ++j) acc[i][j] = (f32x4)0.f;

  const int fr = lane & 15;
  const int fc = lane >> 4;
  const int NT = K / BK;

  auto stage = [&](int buf, int kt) {
#pragma unroll
    for (int j = 0; j < 2; ++j) {
      const int i = wave * 2 + j;
      const long ka = offA[j] + kt;
      const long kb = offB[j] + kt;
      gld16(Ahi_g + ka, &sA[buf][0][i * 512]);
      gld16(Alo_g + ka, &sA[buf][1][i * 512]);
      gld16(Bhi + kb,   &sB[buf][0][i * 512]);
      gld16(Blo + kb,   &sB[buf][1][i * 512]);
    }
  };

  stage(0, 0);
  asm volatile("s_waitcnt vmcnt(0)" ::: "memory");
  __syncthreads();

  for (int t = 0; t < NT; ++t) {
    const int cur = t & 1;
    if (t + 1 < NT) stage(cur ^ 1, (t + 1) * BK);

    short8 fah[4], fal[4], fbh[4], fbl[4];
#pragma unroll
    for (int mi = 0; mi < 4; ++mi) {
      const int idx = (wr + mi * 16 + fr) * BK + fc * 8;
      fah[mi] = *(const short8*)&sA[cur][0][idx];
      fal[mi] = *(const short8*)&sA[cur][1][idx];
    }
#pragma unroll
    for (int ni = 0; ni < 4; ++ni) {
      const int idx = (wc + ni * 16 + fr) * BK + fc * 8;
      fbh[ni] = *(const short8*)&sB[cur][0][idx];
      fbl[ni] = *(const short8*)&sB[cur][1][idx];
    }
#pragma unroll
    for (int mi = 0; mi < 4; ++mi)
#pragma unroll
      for (int ni = 0; ni < 4; ++ni) {
        acc[mi][ni] = __builtin_amdgcn_mfma_f32_16x16x32_bf16(fah[mi], fbh[ni], acc[mi][ni], 0, 0, 0);
        acc[mi][ni] = __builtin_amdgcn_mfma_f32_16x16x32_bf16(fah[mi], fbl[ni], acc[mi][ni], 0, 0, 0);
        acc[mi][ni] = __builtin_amdgcn_mfma_f32_16x16x32_bf16(fal[mi], fbh[ni], acc[mi][ni], 0, 0, 0);
      }
    asm volatile("s_waitcnt vmcnt(0)" ::: "memory");
    __syncthreads();
  }

  // epilogue: C/D layout col=lane&15, row=(lane>>4)*4+rr
#pragma unroll
  for (int mi = 0; mi < 4; ++mi)
#pragma unroll
    for (int rr = 0; rr < 4; ++rr) {
      const int r = mt * 128 + wr + mi * 16 + fc * 4 + rr;
      if (r >= M) continue;
      const long crow = crows ? (long)crows[r] : (cexp * e + r);
#pragma unroll
      for (int ni = 0; ni < 4; ++ni) {
        const int col = n0 + wc + ni * 16 + fr;
        const long off = crow * ldc + col;
        const float v = acc[mi][ni][rr];
        if constexpr (EPI == 1) {
          const float g = G[off];
          const float h = v * (g / (1.f + __expf(-g)));   // silu(g)*u
          unsigned short hh, hl;
          bsplit(h, hh, hl);
          Chi[off] = hh; Clo[off] = hl;
        } else {
          C[off] = v;
        }
      }
    }
}

// ------------- combine: out[t] += sum_k w_k * o_slot[t*4+k] -------------
__global__ __launch_bounds__(256) void combine_kernel(
    const float* __restrict__ o_slot, const float* __restrict__ topw,
    float* __restrict__ out)
{
  const int t = blockIdx.x;
  float w[TOPK];
#pragma unroll
  for (int k = 0; k < TOPK; ++k) w[k] = topw[t * TOPK + k];
  float* orow = out + (size_t)t * HIDDEN;
  for (int c = threadIdx.x * 4; c < HIDDEN; c += 256 * 4) {
    float4 acc = *reinterpret_cast<float4*>(orow + c);
#pragma unroll
    for (int k = 0; k < TOPK; ++k) {
      if (w[k] != 0.f) {
        float4 v = ld4f(o_slot + ((size_t)(t * TOPK + k)) * HIDDEN + c);
        acc.x += w[k] * v.x; acc.y += w[k] * v.y;
        acc.z += w[k] * v.z; acc.w += w[k] * v.w;
      }
    }
    *reinterpret_cast<float4*>(orow + c) = acc;
  }
}

extern "C" void kernel_launch(void* const* d_in, const int* in_sizes, int n_in,
                              void* d_out, int out_size, void* d_ws, size_t ws_size,
                              hipStream_t stream)
{
  const float* x   = (const float*)d_in[0];
  const float* wg  = (const float*)d_in[1];
  const float* w1  = (const float*)d_in[2];
  const float* w3  = (const float*)d_in[3];
  const float* w2  = (const float*)d_in[4];
  const float* ws1 = (const float*)d_in[5];
  const float* ws3 = (const float*)d_in[6];
  const float* ws2 = (const float*)d_in[7];
  float* out = (float*)d_out;

  char* w = (char*)d_ws;
  int*   topi   = (int*)w;   w += (size_t)T_TOKENS * TOPK * 4;
  float* topw   = (float*)w; w += (size_t)T_TOKENS * TOPK * 4;
  int*   rowtok = (int*)w;   w += (size_t)NEXP * CAP * 4;
  int*   count  = (int*)w;   w += 256;
  uintptr_t a = (uintptr_t)w; a = (a + 255) & ~(uintptr_t)255; w = (char*)a;

  const size_t XSZ  = (size_t)T_TOKENS * HIDDEN;          // 4.19M
  const size_t WSSZ = (size_t)HIDDEN * SINTER;            // 5.77M
  const size_t WRSZ = (size_t)NEXP * HIDDEN * INTER;      // 46.1M
  const size_t HSSZ = (size_t)T_TOKENS * SINTER;          // 5.77M
  const size_t HRSZ = (size_t)NEXP * CAP * INTER;         // 17.3M

  unsigned short* xhi  = (unsigned short*)w; w += XSZ * 2;
  unsigned short* xlo  = (unsigned short*)w; w += XSZ * 2;
  unsigned short* wShi = (unsigned short*)w; w += WSSZ * 2;   // rotated ws1T/ws3T/ws2T
  unsigned short* wSlo = (unsigned short*)w; w += WSSZ * 2;
  unsigned short* wRhi = (unsigned short*)w; w += WRSZ * 2;   // rotated w1T/w3T/w2T
  unsigned short* wRlo = (unsigned short*)w; w += WRSZ * 2;
  unsigned short* hShi = (unsigned short*)w; w += HSSZ * 2;
  unsigned short* hSlo = (unsigned short*)w; w += HSSZ * 2;
  unsigned short* hRhi = (unsigned short*)w; w += HRSZ * 2;
  unsigned short* hRlo = (unsigned short*)w; w += HRSZ * 2;
  float* gbuf = (float*)w;   w += (size_t)NEXP * CAP * INTER * 4;  // g_s / g_r / o_slot (69.2 MB)
  float* o_slot = gbuf;      // o_slot [8192][2048] fp32 = 67.1 MB fits in g region

  router_kernel<<<T_TOKENS, 64, 0, stream>>>(x, wg, topi, topw);
  partition_kernel<<<1, 1024, 0, stream>>>(topi, topw, rowtok, count);
  split_x_kernel<<<(int)(XSZ / (256 * 8)), 256, 0, stream>>>(x, xhi, xlo);

  // ---- shared up/gate ----
  tsplit_w_kernel<<<dim3(HIDDEN / 64, SINTER / 64, 1), 256, 0, stream>>>(ws1, wShi, wSlo, HIDDEN, SINTER);
  gemm_bf3<0><<<dim3(SINTER / 128, T_TOKENS / 128, 1), 256, 0, stream>>>(
      xhi, xlo, HIDDEN, wShi, wSlo, 0L, gbuf, nullptr, nullptr, SINTER, nullptr,
      nullptr, 0, 0L, nullptr, 0L, nullptr, T_TOKENS, HIDDEN);
  tsplit_w_kernel<<<dim3(HIDDEN / 64, SINTER / 64, 1), 256, 0, stream>>>(ws3, wShi, wSlo, HIDDEN, SINTER);
  gemm_bf3<1><<<dim3(SINTER / 128, T_TOKENS / 128, 1), 256, 0, stream>>>(
      xhi, xlo, HIDDEN, wShi, wSlo, 0L, nullptr, hShi, hSlo, SINTER, gbuf,
      nullptr, 0, 0L, nullptr, 0L, nullptr, T_TOKENS, HIDDEN);

  // ---- routed up/gate (A rows gathered by token; C rows compact e*CAP+r) ----
  tsplit_w_kernel<<<dim3(HIDDEN / 64, INTER / 64, NEXP), 256, 0, stream>>>(w1, wRhi, wRlo, HIDDEN, INTER);
  gemm_bf3<0><<<dim3(INTER / 128, (CAP + 127) / 128, NEXP), 256, 0, stream>>>(
      xhi, xlo, HIDDEN, wRhi, wRlo, (long)INTER * HIDDEN, gbuf, nullptr, nullptr, INTER, nullptr,
      rowtok, 2, 0L, nullptr, (long)CAP, count, 0, HIDDEN);
  tsplit_w_kernel<<<dim3(HIDDEN / 64, INTER / 64, NEXP), 256, 0, stream>>>(w3, wRhi, wRlo, HIDDEN, INTER);
  gemm_bf3<1><<<dim3(INTER / 128, (CAP + 127) / 128, NEXP), 256, 0, stream>>>(
      xhi, xlo, HIDDEN, wRhi, wRlo, (long)INTER * HIDDEN, nullptr, hRhi, hRlo, INTER, gbuf,
      rowtok, 2, 0L, nullptr, (long)CAP, count, 0, HIDDEN);

  // ---- shared down: out = h_s @ ws2 ----
  tsplit_w_kernel<<<dim3(SINTER / 64, HIDDEN / 64, 1), 256, 0, stream>>>(ws2, wShi, wSlo, SINTER, HIDDEN);
  gemm_bf3<0><<<dim3(HIDDEN / 128, T_TOKENS / 128, 1), 256, 0, stream>>>(
      hShi, hSlo, SINTER, wShi, wSlo, 0L, out, nullptr, nullptr, HIDDEN, nullptr,
      nullptr, 0, 0L, nullptr, 0L, nullptr, T_TOKENS, SINTER);

  // ---- routed down: o_slot = h_r @ w2 (A compact, C scattered to slot ids) ----
  tsplit_w_kernel<<<dim3(INTER / 64, HIDDEN / 64, NEXP), 256, 0, stream>>>(w2, wRhi, wRlo, INTER, HIDDEN);
  gemm_bf3<0><<<dim3(HIDDEN / 128, (CAP + 127) / 128, NEXP), 256, 0, stream>>>(
      hRhi, hRlo, INTER, wRhi, wRlo, (long)HIDDEN * INTER, o_slot, nullptr, nullptr, HIDDEN, nullptr,
      nullptr, 0, (long)CAP, rowtok, 0L, count, 0, INTER);

  combine_kernel<<<T_TOKENS, 256, 0, stream>>>(o_slot, topw, out);
}